// Round 1
// baseline (30256.262 us; speedup 1.0000x reference)
//
#include <hip/hip_runtime.h>
#include <stdint.h>

// GRU stack: B=32, T=2048, I=12, H=512, L=3 + attention epilogue.
// Recurrence strategy: 32 persistent WGs per layer, each owns 16 hidden units
// (48 gate rows). W_hh fragments in VGPRs, W_ih slice in LDS (swizzled).
// Cross-WG h exchange through L3 via sc0/sc1 loads/stores + device-scope flags.
// ws usage ~129 MB (out0/out1 bf16 seq buffers + small scratch).

#define B_ 32
#define T_ 2048
#define H_ 512
#define NWG 32
#define UPW 16

typedef __attribute__((ext_vector_type(8))) short s8v;     // 8 bf16 (4 VGPR)
typedef __attribute__((ext_vector_type(4))) float f4v;     // MFMA acc
typedef __attribute__((ext_vector_type(4))) uint32_t u32x4;

__device__ __forceinline__ uint16_t f2bf(float f){ return __builtin_bit_cast(uint16_t, (__bf16)f); }
__device__ __forceinline__ float bf2f(uint16_t b){ return __builtin_bit_cast(float, ((uint32_t)b)<<16); }

__device__ __forceinline__ s8v pack8(const float* f){
  s8v r;
  #pragma unroll
  for (int i=0;i<8;++i) r[i] = (short)f2bf(f[i]);
  return r;
}
__device__ __forceinline__ f4v mfma16(s8v a, s8v b, f4v c){
  return __builtin_amdgcn_mfma_f32_16x16x32_bf16(a,b,c,0,0,0);
}
#if __has_builtin(__builtin_amdgcn_rcpf)
__device__ __forceinline__ float rcp_(float x){ return __builtin_amdgcn_rcpf(x); }
#else
__device__ __forceinline__ float rcp_(float x){ return 1.0f/x; }
#endif
__device__ __forceinline__ float sigm(float s){ return rcp_(1.f + __expf(-s)); }
__device__ __forceinline__ float tanh2(float v){ return 1.f - 2.f*rcp_(1.f + __expf(2.f*v)); }

// device-coherent (L2-bypassing) access: per-XCD L2s are not coherent, so
// same-kernel cross-WG data must go through L3 (sc0 sc1).
__device__ __forceinline__ u32x4 load_x4_sc(const void* p){
  u32x4 r;
  asm volatile("global_load_dwordx4 %0, %1, off sc0 sc1" : "=v"(r) : "v"(p) : "memory");
  return r;
}
__device__ __forceinline__ void store_s16_sc(void* p, uint32_t v){
  asm volatile("global_store_short %0, %1, off sc0 sc1" :: "v"(p), "v"(v) : "memory");
}

__global__ void init_kernel(const float* __restrict__ vel_init,
    const float* __restrict__ w0, const float* __restrict__ b0,
    const float* __restrict__ w1, const float* __restrict__ b1,
    const float* __restrict__ w2, const float* __restrict__ b2,
    float* __restrict__ h0f, uint16_t* __restrict__ h0b, uint32_t* flags)
{
  const int l = blockIdx.x, tid = threadIdx.x;
  const float* w  = (l==0)?w0:((l==1)?w1:w2);
  const float* bb = (l==0)?b0:((l==1)?b1:b2);
  for (int idx = tid; idx < B_*H_; idx += 256){
    int b = idx >> 9, j = idx & 511;
    float s = bb[j] + vel_init[b*3+0]*w[j*3+0] + vel_init[b*3+1]*w[j*3+1]
                    + vel_init[b*3+2]*w[j*3+2];
    h0f[(size_t)l*(B_*H_) + idx] = s;
    h0b[(size_t)l*(B_*H_) + idx] = f2bf(s);
  }
  if (l == 0 && tid < 96) flags[tid] = 0;   // 3 layers x 32 WGs
}

template<bool FIRST>
__global__ __launch_bounds__(128, 1) void scan_kernel(
    const void* __restrict__ inp_, const float* __restrict__ w_ih,
    const float* __restrict__ w_hh, const float* __restrict__ b_ih,
    const float* __restrict__ b_hh, const float* __restrict__ h0f,
    const uint16_t* __restrict__ h0b, uint16_t* __restrict__ outp,
    uint32_t* flags)
{
  const int tid  = threadIdx.x;
  const int lane = tid & 63;
  const int mt   = tid >> 6;            // wave = batch tile (0/1)
  const int wg   = blockIdx.x;          // 0..31
  const int j0   = wg * UPW;
  const int u    = lane & 15;           // unit col / A row
  const int ko   = (lane >> 4) * 8;     // k octet
  const int bd   = (lane >> 4) * 4;     // D row base

  __shared__ uint16_t lds[FIRST ? (2*16*32) : (48*512)];

  float bihv[3], bhhv[3];
  #pragma unroll
  for (int nt=0; nt<3; ++nt){
    bihv[nt] = b_ih[nt*H_ + j0 + u];
    bhhv[nt] = b_hh[nt*H_ + j0 + u];
  }

  // W_hh B-fragments resident in VGPRs (48 frags = 192 VGPR/lane)
  s8v whh[3][16];
  #pragma unroll
  for (int nt=0; nt<3; ++nt){
    #pragma unroll
    for (int ks=0; ks<16; ++ks){
      const float* wp = w_hh + (size_t)(nt*H_ + j0 + u)*H_ + ks*32 + ko;
      float tmp[8];
      #pragma unroll
      for (int i=0;i<8;++i) tmp[i] = wp[i];
      whh[nt][ks] = pack8(tmp);
    }
  }

  s8v w0f[3];
  int xbs[3], xks[3];
  if (FIRST) {
    #pragma unroll
    for (int nt=0; nt<3; ++nt){
      float tmp[8];
      #pragma unroll
      for (int i=0;i<8;++i){
        int k = ko + i;
        tmp[i] = (k < 12) ? w_ih[(size_t)(nt*H_ + j0 + u)*12 + k] : 0.f;
      }
      w0f[nt] = pack8(tmp);
    }
    for (int e = tid; e < 2*16*32; e += 128) lds[e] = 0;  // zero-padded x stage
    #pragma unroll
    for (int s=0;s<3;++s){ int idx = lane + 64*s; xbs[s] = idx/12; xks[s] = idx%12; }
  } else {
    // stage W_ih slice to LDS, bf16, XOR-swizzled 16B chunks (bank-conflict fix)
    for (int e = tid; e < (48*512)/8; e += 128) {
      int idx = e * 8;
      int g = idx >> 9, k = idx & 511;
      const float* wp = w_ih + (size_t)((g>>4)*H_ + j0 + (g&15))*H_ + k;
      float tmp[8];
      #pragma unroll
      for (int i=0;i<8;++i) tmp[i] = wp[i];
      s8v v = pack8(tmp);
      uint32_t off = (uint32_t)g*1024u + ((((uint32_t)k)*2u) ^ (uint32_t)((g&7)<<4));
      *(u32x4*)((char*)lds + off) = __builtin_bit_cast(u32x4, v);
    }
  }
  __syncthreads();

  // fp32 hidden-state carry (z*h term stays full precision)
  float hold[4];
  #pragma unroll
  for (int r=0;r<4;++r) hold[r] = h0f[(size_t)(mt*16 + bd + r)*H_ + j0 + u];

  const uint32_t sw  = (uint32_t)((u & 7) << 4);
  const uint32_t gb0 = (uint32_t)((0*16 + u) * 1024);
  const uint32_t gb1 = (uint32_t)((1*16 + u) * 1024);
  const uint32_t gb2 = (uint32_t)((2*16 + u) * 1024);
  const uint32_t koB = (uint32_t)(((lane >> 4) * 8) * 2);

  for (int t = 0; t < T_; ++t) {
    // ---- x-part (independent of h_{t-1}) ----
    f4v ax0 = {0,0,0,0}, ax1 = {0,0,0,0}, ax2 = {0,0,0,0};
    if (FIRST) {
      const float* x = (const float*)inp_;
      #pragma unroll
      for (int s=0;s<3;++s){
        float xv = x[((size_t)(mt*16 + xbs[s])*T_ + (size_t)t)*12 + xks[s]];
        lds[mt*512 + xbs[s]*32 + xks[s]] = f2bf(xv);
      }
      s8v a = *(const s8v*)&lds[mt*512 + u*32 + ko];
      ax0 = mfma16(a, w0f[0], ax0);
      ax1 = mfma16(a, w0f[1], ax1);
      ax2 = mfma16(a, w0f[2], ax2);
    } else {
      const uint16_t* xin = (const uint16_t*)inp_ + (size_t)t*(B_*H_)
                            + (size_t)(mt*16 + u)*H_ + ko;
      #pragma unroll
      for (int ks=0; ks<16; ++ks){
        u32x4 q = *(const u32x4*)(xin + ks*32);
        s8v a = __builtin_bit_cast(s8v, q);
        uint32_t kk = ((uint32_t)(ks*64) + koB) ^ sw;
        s8v w0 = *(const s8v*)((const char*)lds + gb0 + kk);
        s8v w1 = *(const s8v*)((const char*)lds + gb1 + kk);
        s8v w2 = *(const s8v*)((const char*)lds + gb2 + kk);
        ax0 = mfma16(a, w0, ax0);
        ax1 = mfma16(a, w1, ax1);
        ax2 = mfma16(a, w2, ax2);
      }
    }

    // ---- wait for h_{t-1} from all WGs ----
    if (t > 0) {
      const uint32_t tgt = (uint32_t)t;
      while (1) {
        uint32_t f = __hip_atomic_load(&flags[lane & 31], __ATOMIC_RELAXED,
                                       __HIP_MEMORY_SCOPE_AGENT);
        if (__ballot(f >= tgt) == ~0ull) break;
      }
      asm volatile("" ::: "memory");
    }

    // ---- h-part: coherent loads of full h_{t-1} ----
    const uint16_t* hsrc = (t == 0) ? h0b : (outp + (size_t)(t-1)*(B_*H_));
    const uint16_t* hp = hsrc + (size_t)(mt*16 + u)*H_ + ko;
    u32x4 ha[16];
    #pragma unroll
    for (int ks=0; ks<16; ++ks) ha[ks] = load_x4_sc(hp + ks*32);
    asm volatile("s_waitcnt vmcnt(0)" ::: "memory");
    __builtin_amdgcn_sched_barrier(0);

    f4v ah0 = {0,0,0,0}, ah1 = {0,0,0,0}, ah2 = {0,0,0,0};
    #pragma unroll
    for (int ks=0; ks<16; ++ks){
      s8v a = __builtin_bit_cast(s8v, ha[ks]);
      ah0 = mfma16(a, whh[0][ks], ah0);
      ah1 = mfma16(a, whh[1][ks], ah1);
      ah2 = mfma16(a, whh[2][ks], ah2);
    }

    // ---- gates (lane-local: r,z,n for unit j0+u, 4 batches) ----
    uint16_t* orow = outp + (size_t)t*(B_*H_) + (size_t)(mt*16 + bd)*H_ + j0 + u;
    #pragma unroll
    for (int r=0;r<4;++r){
      float xr = ax0[r] + bihv[0], hr = ah0[r] + bhhv[0];
      float xz = ax1[r] + bihv[1], hz = ah1[r] + bhhv[1];
      float xn = ax2[r] + bihv[2], hn = ah2[r] + bhhv[2];
      float rg = sigm(xr + hr);
      float zg = sigm(xz + hz);
      float ng = tanh2(xn + rg*hn);
      float hv = ng + zg*(hold[r] - ng);
      hold[r] = hv;
      store_s16_sc(orow + (size_t)r*H_, (uint32_t)f2bf(hv));
    }

    // ---- publish step ----
    asm volatile("s_waitcnt vmcnt(0)" ::: "memory");
    __syncthreads();
    if (tid == 0)
      __hip_atomic_store(&flags[wg], (uint32_t)(t+1), __ATOMIC_RELEASE,
                         __HIP_MEMORY_SCOPE_AGENT);
  }
}

__global__ void scores_kernel(const uint16_t* __restrict__ out2,
    const float* __restrict__ attn_w, const float* __restrict__ attn_b,
    const float* __restrict__ a1, float* __restrict__ scores)
{
  int gw = (blockIdx.x * blockDim.x + threadIdx.x) >> 6;
  int lane = threadIdx.x & 63;
  int b = gw >> 11, t = gw & 2047;
  float alpha = a1[0];
  u32x4 q = *(const u32x4*)(out2 + ((size_t)t*B_ + b)*H_ + lane*8);
  const uint16_t* ob = (const uint16_t*)&q;
  const float* aw = attn_w + lane*8;
  float acc = 0.f;
  #pragma unroll
  for (int i=0;i<8;++i){
    float ov = bf2f(ob[i]);
    ov = (ov >= 0.f) ? ov : alpha*ov;
    acc += ov * aw[i];
  }
  #pragma unroll
  for (int off=32; off>0; off>>=1) acc += __shfl_xor(acc, off, 64);
  if (lane == 0) scores[(size_t)b*T_ + t] = acc + attn_b[0];
}

__global__ void softmax_kernel(const float* __restrict__ scores, float* __restrict__ attn)
{
  int b = blockIdx.x, tid = threadIdx.x;
  __shared__ float red[256];
  const float* row = scores + (size_t)b*T_;
  float v[8]; float m = -3.4e38f;
  #pragma unroll
  for (int i=0;i<8;++i){ v[i] = row[tid + i*256]; m = fmaxf(m, v[i]); }
  red[tid] = m; __syncthreads();
  for (int s=128; s>0; s>>=1){ if (tid < s) red[tid] = fmaxf(red[tid], red[tid+s]); __syncthreads(); }
  m = red[0]; __syncthreads();
  float sum = 0.f;
  #pragma unroll
  for (int i=0;i<8;++i){ v[i] = __expf(v[i]-m); sum += v[i]; }
  red[tid] = sum; __syncthreads();
  for (int s=128; s>0; s>>=1){ if (tid < s) red[tid] += red[tid+s]; __syncthreads(); }
  float inv = 1.f / red[0];
  #pragma unroll
  for (int i=0;i<8;++i) attn[(size_t)b*T_ + tid + i*256] = v[i]*inv;
}

__global__ void final_kernel(const uint16_t* __restrict__ out2, const float* __restrict__ x,
    const float* __restrict__ attn, const float* __restrict__ dw, const float* __restrict__ db,
    const float* __restrict__ vw, const float* __restrict__ vb,
    const float* __restrict__ swt, const float* __restrict__ sb,
    const float* __restrict__ a1, float* __restrict__ dout)
{
  int gw = (blockIdx.x * blockDim.x + threadIdx.x) >> 6;
  int lane = threadIdx.x & 63;
  int b = gw >> 11, t = gw & 2047;
  float alpha = a1[0];
  u32x4 q = *(const u32x4*)(out2 + ((size_t)t*B_ + b)*H_ + lane*8);
  const uint16_t* ob = (const uint16_t*)&q;
  const float* xp = x + ((size_t)b*T_ + t)*12;
  float xr[12];
  #pragma unroll
  for (int i=0;i<12;++i) xr[i] = xp[i];
  float av = attn[(size_t)b*T_ + t];
  float acc[6] = {0,0,0,0,0,0};
  #pragma unroll
  for (int k=0;k<8;++k){
    int j = lane*8 + k;
    float ov = bf2f(ob[k]);
    ov = (ov >= 0.f) ? ov : alpha*ov;
    float d = db[j];
    const float* dwp = dw + (size_t)j*12;
    #pragma unroll
    for (int i=0;i<12;++i) d += xr[i]*dwp[i];
    float uo = ov + av*d;
    #pragma unroll
    for (int o=0;o<3;++o){
      acc[o]   += uo * vw[(size_t)o*H_ + j];
      acc[3+o] += uo * swt[(size_t)o*H_ + j];
    }
  }
  #pragma unroll
  for (int o=0;o<6;++o){
    #pragma unroll
    for (int off=32; off>0; off>>=1) acc[o] += __shfl_xor(acc[o], off, 64);
  }
  if (lane == 0){
    size_t p = ((size_t)b*T_ + t)*3;
    #pragma unroll
    for (int o=0;o<3;++o){
      dout[p + o] = acc[o] + vb[o];
      dout[(size_t)B_*T_*3 + p + o] = acc[3+o] + sb[o];
    }
  }
}

extern "C" void kernel_launch(void* const* d_in, const int* in_sizes, int n_in,
                              void* d_out, int out_size, void* d_ws, size_t ws_size,
                              hipStream_t stream)
{
  (void)in_sizes; (void)n_in; (void)out_size; (void)ws_size;
  const float* x        = (const float*)d_in[0];
  const float* vel_init = (const float*)d_in[1];
  const float* w_ih[3] = {(const float*)d_in[2], (const float*)d_in[6],  (const float*)d_in[10]};
  const float* w_hh[3] = {(const float*)d_in[3], (const float*)d_in[7],  (const float*)d_in[11]};
  const float* b_ih[3] = {(const float*)d_in[4], (const float*)d_in[8],  (const float*)d_in[12]};
  const float* b_hh[3] = {(const float*)d_in[5], (const float*)d_in[9],  (const float*)d_in[13]};
  const float* a1     = (const float*)d_in[14];
  const float* dec_w  = (const float*)d_in[15];
  const float* dec_b  = (const float*)d_in[16];
  const float* vd_w[3] = {(const float*)d_in[17], (const float*)d_in[19], (const float*)d_in[21]};
  const float* vd_b[3] = {(const float*)d_in[18], (const float*)d_in[20], (const float*)d_in[22]};
  const float* vel_w  = (const float*)d_in[23];
  const float* vel_b  = (const float*)d_in[24];
  const float* std_w  = (const float*)d_in[25];
  const float* std_b  = (const float*)d_in[26];
  const float* attn_w = (const float*)d_in[27];
  const float* attn_b = (const float*)d_in[28];

  char* ws = (char*)d_ws;                       // requires ~129 MB workspace
  uint16_t* out0   = (uint16_t*)(ws);
  uint16_t* out1   = (uint16_t*)(ws + (size_t)67108864);
  float*    h0f    = (float*)   (ws + (size_t)134217728);
  uint16_t* h0b    = (uint16_t*)(ws + (size_t)134414336);
  float*    scores = (float*)   (ws + (size_t)134512640);
  float*    attnp  = (float*)   (ws + (size_t)134774784);
  uint32_t* flags  = (uint32_t*)(ws + (size_t)135036928);

  init_kernel<<<3, 256, 0, stream>>>(vel_init, vd_w[0], vd_b[0], vd_w[1], vd_b[1],
                                     vd_w[2], vd_b[2], h0f, h0b, flags);
  scan_kernel<true ><<<NWG, 128, 0, stream>>>(x,    w_ih[0], w_hh[0], b_ih[0], b_hh[0],
                                              h0f,            h0b,            out0, flags);
  scan_kernel<false><<<NWG, 128, 0, stream>>>(out0, w_ih[1], w_hh[1], b_ih[1], b_hh[1],
                                              h0f + B_*H_,    h0b + B_*H_,    out1, flags + 32);
  scan_kernel<false><<<NWG, 128, 0, stream>>>(out1, w_ih[2], w_hh[2], b_ih[2], b_hh[2],
                                              h0f + 2*B_*H_,  h0b + 2*B_*H_,  out0, flags + 64);
  scores_kernel<<<(B_*T_)/4, 256, 0, stream>>>(out0, attn_w, attn_b, a1, scores);
  softmax_kernel<<<B_, 256, 0, stream>>>(scores, attnp);
  final_kernel<<<(B_*T_)/4, 256, 0, stream>>>(out0, x, attnp, dec_w, dec_b,
                                              vel_w, vel_b, std_w, std_b, a1, (float*)d_out);
}

// Round 2
// 12260.028 us; speedup vs baseline: 2.4679x; 2.4679x over previous
//
#include <hip/hip_runtime.h>
#include <stdint.h>

// Fused 3-layer GRU pipeline: B=32, T=2048, I=12, H=512.
// 96 persistent WGs (32 per layer, 16 hidden units each). Layers pipeline with
// lag 1 (serial depth ~2050 instead of 6144). Inter-layer streams go through
// 128-step ring buffers (L2/L3-hot). Cross-WG h + stream exchange via sc0/sc1
// (device-coherent) loads/stores + per-WG step flags.

#define B_ 32
#define T_ 2048
#define H_ 512
#define R_ 128          // ring depth (steps); backpressure keeps producers < R ahead

typedef __attribute__((ext_vector_type(8))) short s8v;     // 8 bf16 (4 VGPR)
typedef __attribute__((ext_vector_type(4))) float f4v;     // MFMA acc
typedef __attribute__((ext_vector_type(4))) uint32_t u32x4;

__device__ __forceinline__ uint16_t f2bf(float f){ return __builtin_bit_cast(uint16_t, (__bf16)f); }
__device__ __forceinline__ float bf2f(uint16_t b){ return __builtin_bit_cast(float, ((uint32_t)b)<<16); }

__device__ __forceinline__ s8v pack8(const float* f){
  s8v r;
  #pragma unroll
  for (int i=0;i<8;++i) r[i] = (short)f2bf(f[i]);
  return r;
}
__device__ __forceinline__ f4v mfma16(s8v a, s8v b, f4v c){
  return __builtin_amdgcn_mfma_f32_16x16x32_bf16(a,b,c,0,0,0);
}
#if __has_builtin(__builtin_amdgcn_rcpf)
__device__ __forceinline__ float rcp_(float x){ return __builtin_amdgcn_rcpf(x); }
#else
__device__ __forceinline__ float rcp_(float x){ return 1.0f/x; }
#endif
__device__ __forceinline__ float sigm(float s){ return rcp_(1.f + __expf(-s)); }
__device__ __forceinline__ float tanh2(float v){ return 1.f - 2.f*rcp_(1.f + __expf(2.f*v)); }

// device-coherent ops (bypass non-coherent per-XCD L2, served by L3)
__device__ __forceinline__ u32x4 load_x4_sc(const void* p){
  u32x4 r;
  asm volatile("global_load_dwordx4 %0, %1, off sc0 sc1" : "=v"(r) : "v"(p) : "memory");
  return r;
}
__device__ __forceinline__ uint32_t load_u32_sc_wait(const void* p){
  uint32_t r;
  asm volatile("global_load_dword %0, %1, off sc0 sc1\n\ts_waitcnt vmcnt(0)"
               : "=v"(r) : "v"(p) : "memory");
  return r;
}
__device__ __forceinline__ void store_s16_sc(void* p, uint32_t v){
  asm volatile("global_store_short %0, %1, off sc0 sc1" :: "v"(p), "v"(v) : "memory");
}
__device__ __forceinline__ void store_u32_sc(void* p, uint32_t v){
  asm volatile("global_store_dword %0, %1, off sc0 sc1" :: "v"(p), "v"(v) : "memory");
}

__global__ void init_kernel(const float* __restrict__ vel_init,
    const float* __restrict__ w0, const float* __restrict__ b0,
    const float* __restrict__ w1, const float* __restrict__ b1,
    const float* __restrict__ w2, const float* __restrict__ b2,
    float* __restrict__ h0f, uint16_t* __restrict__ h0b, uint32_t* flags)
{
  const int l = blockIdx.x, tid = threadIdx.x;
  const float* w  = (l==0)?w0:((l==1)?w1:w2);
  const float* bb = (l==0)?b0:((l==1)?b1:b2);
  for (int idx = tid; idx < B_*H_; idx += 256){
    int b = idx >> 9, j = idx & 511;
    float s = bb[j] + vel_init[b*3+0]*w[j*3+0] + vel_init[b*3+1]*w[j*3+1]
                    + vel_init[b*3+2]*w[j*3+2];
    h0f[(size_t)l*(B_*H_) + idx] = s;
    h0b[(size_t)l*(B_*H_) + idx] = f2bf(s);
  }
  if (l == 0 && tid < 96) flags[tid] = 0;   // 3 layers x 32 WGs
}

struct ScanParams {
  const float* x;
  const float* wih[3];
  const float* whh[3];
  const float* bih[3];
  const float* bhh[3];
  const float* h0f;
  const uint16_t* h0b;
  uint16_t* ring0;   // [R_][B][H] bf16, layer0 -> layer1
  uint16_t* ring1;   // [R_][B][H] bf16, layer1 -> layer2
  uint16_t* out2;    // [T][B][H] bf16, layer2 output (epilogue input)
  uint32_t* flags;   // [3][32]
};

__global__ __launch_bounds__(128, 1) void fused_scan(ScanParams P)
{
  const int tid  = threadIdx.x;
  const int lane = tid & 63;
  const int mt   = tid >> 6;            // wave = batch tile (0/1)
  const int wgid = blockIdx.x;          // 0..95
  const int layer = wgid >> 5;          // 0..2
  const int wg   = wgid & 31;
  const int j0   = wg * 16;
  const int u    = lane & 15;           // unit col / A row
  const int ko   = (lane >> 4) * 8;     // k octet
  const int bd   = (lane >> 4) * 4;     // D row base

  __shared__ uint16_t lds[48*512];      // wih slice (layers 1,2); unused layer 0

  const float* wih = P.wih[layer];
  const float* whh = P.whh[layer];
  const float* bih = P.bih[layer];
  const float* bhh = P.bhh[layer];

  // merged biases: r,z gates fold b_ih+b_hh; n gate needs them split
  const float bs0 = bih[0*H_ + j0 + u] + bhh[0*H_ + j0 + u];
  const float bs1 = bih[1*H_ + j0 + u] + bhh[1*H_ + j0 + u];
  const float bi2 = bih[2*H_ + j0 + u];
  const float bh2 = bhh[2*H_ + j0 + u];

  // W_hh B-fragments resident in VGPRs (48 frags = 192 VGPR/lane)
  s8v whhf[3][16];
  #pragma unroll
  for (int nt=0; nt<3; ++nt){
    #pragma unroll
    for (int ks=0; ks<16; ++ks){
      const float* wp = whh + (size_t)(nt*H_ + j0 + u)*H_ + ks*32 + ko;
      float tmp[8];
      #pragma unroll
      for (int i=0;i<8;++i) tmp[i] = wp[i];
      whhf[nt][ks] = pack8(tmp);
    }
  }

  s8v w0f[3];
  if (layer == 0){
    #pragma unroll
    for (int nt=0; nt<3; ++nt){
      float tmp[8];
      #pragma unroll
      for (int i=0;i<8;++i){
        int k = ko + i;
        tmp[i] = (k < 12) ? wih[(size_t)(nt*H_ + j0 + u)*12 + k] : 0.f;
      }
      w0f[nt] = pack8(tmp);
    }
  } else {
    // stage W_ih slice to LDS, bf16, XOR-swizzled 16B chunks
    for (int e = tid; e < (48*512)/8; e += 128) {
      int idx = e * 8;
      int g = idx >> 9, k = idx & 511;
      const float* wp = wih + (size_t)((g>>4)*H_ + j0 + (g&15))*H_ + k;
      float tmp[8];
      #pragma unroll
      for (int i=0;i<8;++i) tmp[i] = wp[i];
      s8v v = pack8(tmp);
      uint32_t off = (uint32_t)g*1024u + ((((uint32_t)k)*2u) ^ (uint32_t)((g&7)<<4));
      *(u32x4*)((char*)lds + off) = __builtin_bit_cast(u32x4, v);
    }
  }
  __syncthreads();

  // role pointers
  uint32_t* ownf  = P.flags + layer*32;
  uint32_t* prodf = (layer>0) ? (P.flags + (layer-1)*32) : nullptr;
  uint32_t* consf = (layer<2) ? (P.flags + (layer+1)*32) : nullptr;
  const uint16_t* inring = (layer==1) ? P.ring0 : P.ring1;  // layer0 unused
  uint16_t* outbuf = (layer==0) ? P.ring0 : ((layer==1) ? P.ring1 : P.out2);
  const bool outlin = (layer == 2);

  // fp32 hidden-state carry
  float hold[4];
  #pragma unroll
  for (int r=0;r<4;++r)
    hold[r] = P.h0f[(size_t)layer*(B_*H_) + (size_t)(mt*16 + bd + r)*H_ + j0 + u];

  const uint32_t sw  = (uint32_t)((u & 7) << 4);
  const uint32_t gb0 = (uint32_t)((0*16 + u) * 1024);
  const uint32_t gb1 = (uint32_t)((1*16 + u) * 1024);
  const uint32_t gb2 = (uint32_t)((2*16 + u) * 1024);
  const uint32_t koB = (uint32_t)(ko * 2);
  const int fl = lane & 31;

  for (int t = 0; t < T_; ++t) {
    f4v ac0 = {0,0,0,0}, ac1 = {0,0,0,0}, axn = {0,0,0,0}, ahn = {0,0,0,0};

    // ---- layer-0 x-part: fully off the critical path (input is static) ----
    if (layer == 0) {
      const float* xp = P.x + ((size_t)(mt*16 + u)*T_ + (size_t)t)*12;
      float4 lo  = *(const float4*)(xp);
      float4 md  = *(const float4*)(xp + 4);
      float4 hi4 = *(const float4*)(xp + 8);
      float xv[8];
      xv[0] = (ko==0) ? lo.x : hi4.x;  xv[1] = (ko==0) ? lo.y : hi4.y;
      xv[2] = (ko==0) ? lo.z : hi4.z;  xv[3] = (ko==0) ? lo.w : hi4.w;
      xv[4] = (ko==0) ? md.x : 0.f;    xv[5] = (ko==0) ? md.y : 0.f;
      xv[6] = (ko==0) ? md.z : 0.f;    xv[7] = (ko==0) ? md.w : 0.f;
      s8v a = pack8(xv);
      ac0 = mfma16(a, w0f[0], ac0);
      ac1 = mfma16(a, w0f[1], ac1);
      axn = mfma16(a, w0f[2], axn);
    }

    // ---- combined poll: own h ready, input ready, consumer backpressure ----
    if (t > 0 || layer > 0) {
      while (1) {
        bool ok;
        if (lane < 32) {
          ok = (int)load_u32_sc_wait(ownf + fl) >= t;
          if (consf && t >= R_)
            ok = ok && ((int)load_u32_sc_wait(consf + fl) >= (t + 1 - R_));
        } else {
          ok = (prodf == nullptr) || ((int)load_u32_sc_wait(prodf + fl) >= (t + 1));
        }
        if (__ballot(ok) == ~0ull) break;
      }
    }

    // ---- issue input loads (layers 1,2), then h loads ----
    u32x4 xa[16], ha[16];
    if (layer > 0) {
      const uint16_t* xin = inring + (size_t)(t & (R_-1))*(B_*H_)
                            + (size_t)(mt*16 + u)*H_ + ko;
      #pragma unroll
      for (int ks=0; ks<16; ++ks) xa[ks] = load_x4_sc(xin + ks*32);
    }
    const uint16_t* hsrc = (t == 0)
        ? (P.h0b + (size_t)layer*(B_*H_))
        : (outlin ? (P.out2 + (size_t)(t-1)*(B_*H_))
                  : (outbuf + (size_t)((t-1) & (R_-1))*(B_*H_)));
    const uint16_t* hp = hsrc + (size_t)(mt*16 + u)*H_ + ko;
    #pragma unroll
    for (int ks=0; ks<16; ++ks) ha[ks] = load_x4_sc(hp + ks*32);

    // ---- x-MFMAs while h loads are still in flight ----
    if (layer > 0) {
      asm volatile("s_waitcnt vmcnt(16)" ::: "memory");  // input (older 16) done
      __builtin_amdgcn_sched_barrier(0);
      #pragma unroll
      for (int ks=0; ks<16; ++ks){
        s8v a = __builtin_bit_cast(s8v, xa[ks]);
        uint32_t kk = ((uint32_t)(ks*64) + koB) ^ sw;
        s8v w0 = *(const s8v*)((const char*)lds + gb0 + kk);
        s8v w1 = *(const s8v*)((const char*)lds + gb1 + kk);
        s8v w2 = *(const s8v*)((const char*)lds + gb2 + kk);
        ac0 = mfma16(a, w0, ac0);
        ac1 = mfma16(a, w1, ac1);
        axn = mfma16(a, w2, axn);
      }
    }

    asm volatile("s_waitcnt vmcnt(0)" ::: "memory");
    __builtin_amdgcn_sched_barrier(0);
    #pragma unroll
    for (int ks=0; ks<16; ++ks){
      s8v a = __builtin_bit_cast(s8v, ha[ks]);
      ac0 = mfma16(a, whhf[0][ks], ac0);
      ac1 = mfma16(a, whhf[1][ks], ac1);
      ahn = mfma16(a, whhf[2][ks], ahn);
    }

    // ---- gates (lane-local) + coherent store ----
    uint16_t* orow = outbuf
        + (outlin ? (size_t)t*(B_*H_) : (size_t)(t & (R_-1))*(B_*H_))
        + (size_t)(mt*16 + bd)*H_ + j0 + u;
    #pragma unroll
    for (int r=0;r<4;++r){
      float rg = sigm(ac0[r] + bs0);
      float zg = sigm(ac1[r] + bs1);
      float ng = tanh2(axn[r] + bi2 + rg*(ahn[r] + bh2));
      float hv = ng + zg*(hold[r] - ng);
      hold[r] = hv;
      store_s16_sc(orow + (size_t)r*H_, (uint32_t)f2bf(hv));
    }

    // ---- publish step ----
    asm volatile("s_waitcnt vmcnt(0)" ::: "memory");
    __syncthreads();
    if (tid == 0) store_u32_sc(ownf + wg, (uint32_t)(t + 1));
  }
}

__global__ void scores_kernel(const uint16_t* __restrict__ out2,
    const float* __restrict__ attn_w, const float* __restrict__ attn_b,
    const float* __restrict__ a1, float* __restrict__ scores)
{
  int gw = (blockIdx.x * blockDim.x + threadIdx.x) >> 6;
  int lane = threadIdx.x & 63;
  int b = gw >> 11, t = gw & 2047;
  float alpha = a1[0];
  u32x4 q = *(const u32x4*)(out2 + ((size_t)t*B_ + b)*H_ + lane*8);
  const uint16_t* ob = (const uint16_t*)&q;
  const float* aw = attn_w + lane*8;
  float acc = 0.f;
  #pragma unroll
  for (int i=0;i<8;++i){
    float ov = bf2f(ob[i]);
    ov = (ov >= 0.f) ? ov : alpha*ov;
    acc += ov * aw[i];
  }
  #pragma unroll
  for (int off=32; off>0; off>>=1) acc += __shfl_xor(acc, off, 64);
  if (lane == 0) scores[(size_t)b*T_ + t] = acc + attn_b[0];
}

__global__ void softmax_kernel(const float* __restrict__ scores, float* __restrict__ attn)
{
  int b = blockIdx.x, tid = threadIdx.x;
  __shared__ float red[256];
  const float* row = scores + (size_t)b*T_;
  float v[8]; float m = -3.4e38f;
  #pragma unroll
  for (int i=0;i<8;++i){ v[i] = row[tid + i*256]; m = fmaxf(m, v[i]); }
  red[tid] = m; __syncthreads();
  for (int s=128; s>0; s>>=1){ if (tid < s) red[tid] = fmaxf(red[tid], red[tid+s]); __syncthreads(); }
  m = red[0]; __syncthreads();
  float sum = 0.f;
  #pragma unroll
  for (int i=0;i<8;++i){ v[i] = __expf(v[i]-m); sum += v[i]; }
  red[tid] = sum; __syncthreads();
  for (int s=128; s>0; s>>=1){ if (tid < s) red[tid] += red[tid+s]; __syncthreads(); }
  float inv = 1.f / red[0];
  #pragma unroll
  for (int i=0;i<8;++i) attn[(size_t)b*T_ + tid + i*256] = v[i]*inv;
}

__global__ void final_kernel(const uint16_t* __restrict__ out2, const float* __restrict__ x,
    const float* __restrict__ attn, const float* __restrict__ dw, const float* __restrict__ db,
    const float* __restrict__ vw, const float* __restrict__ vb,
    const float* __restrict__ swt, const float* __restrict__ sb,
    const float* __restrict__ a1, float* __restrict__ dout)
{
  int gw = (blockIdx.x * blockDim.x + threadIdx.x) >> 6;
  int lane = threadIdx.x & 63;
  int b = gw >> 11, t = gw & 2047;
  float alpha = a1[0];
  u32x4 q = *(const u32x4*)(out2 + ((size_t)t*B_ + b)*H_ + lane*8);
  const uint16_t* ob = (const uint16_t*)&q;
  const float* xp = x + ((size_t)b*T_ + t)*12;
  float xr[12];
  #pragma unroll
  for (int i=0;i<12;++i) xr[i] = xp[i];
  float av = attn[(size_t)b*T_ + t];
  float acc[6] = {0,0,0,0,0,0};
  #pragma unroll
  for (int k=0;k<8;++k){
    int j = lane*8 + k;
    float ov = bf2f(ob[k]);
    ov = (ov >= 0.f) ? ov : alpha*ov;
    float d = db[j];
    const float* dwp = dw + (size_t)j*12;
    #pragma unroll
    for (int i=0;i<12;++i) d += xr[i]*dwp[i];
    float uo = ov + av*d;
    #pragma unroll
    for (int o=0;o<3;++o){
      acc[o]   += uo * vw[(size_t)o*H_ + j];
      acc[3+o] += uo * swt[(size_t)o*H_ + j];
    }
  }
  #pragma unroll
  for (int o=0;o<6;++o){
    #pragma unroll
    for (int off=32; off>0; off>>=1) acc[o] += __shfl_xor(acc[o], off, 64);
  }
  if (lane == 0){
    size_t p = ((size_t)b*T_ + t)*3;
    #pragma unroll
    for (int o=0;o<3;++o){
      dout[p + o] = acc[o] + vb[o];
      dout[(size_t)B_*T_*3 + p + o] = acc[3+o] + sb[o];
    }
  }
}

extern "C" void kernel_launch(void* const* d_in, const int* in_sizes, int n_in,
                              void* d_out, int out_size, void* d_ws, size_t ws_size,
                              hipStream_t stream)
{
  (void)in_sizes; (void)n_in; (void)out_size; (void)ws_size;
  const float* x        = (const float*)d_in[0];
  const float* vel_init = (const float*)d_in[1];
  const float* w_ih[3] = {(const float*)d_in[2], (const float*)d_in[6],  (const float*)d_in[10]};
  const float* w_hh[3] = {(const float*)d_in[3], (const float*)d_in[7],  (const float*)d_in[11]};
  const float* b_ih[3] = {(const float*)d_in[4], (const float*)d_in[8],  (const float*)d_in[12]};
  const float* b_hh[3] = {(const float*)d_in[5], (const float*)d_in[9],  (const float*)d_in[13]};
  const float* a1     = (const float*)d_in[14];
  const float* dec_w  = (const float*)d_in[15];
  const float* dec_b  = (const float*)d_in[16];
  const float* vd_w[3] = {(const float*)d_in[17], (const float*)d_in[19], (const float*)d_in[21]};
  const float* vd_b[3] = {(const float*)d_in[18], (const float*)d_in[20], (const float*)d_in[22]};
  const float* vel_w  = (const float*)d_in[23];
  const float* vel_b  = (const float*)d_in[24];
  const float* std_w  = (const float*)d_in[25];
  const float* std_b  = (const float*)d_in[26];
  const float* attn_w = (const float*)d_in[27];
  const float* attn_b = (const float*)d_in[28];

  char* ws = (char*)d_ws;                         // ~76.4 MB used
  uint16_t* out2   = (uint16_t*)(ws);                      // 64 MB
  uint16_t* ring0  = (uint16_t*)(ws + (size_t)67108864);   // 4 MB
  uint16_t* ring1  = (uint16_t*)(ws + (size_t)71303168);   // 4 MB
  float*    h0f    = (float*)   (ws + (size_t)75497472);   // 192 KB
  uint16_t* h0b    = (uint16_t*)(ws + (size_t)75694080);   // 96 KB
  float*    scores = (float*)   (ws + (size_t)75792384);   // 256 KB
  float*    attnp  = (float*)   (ws + (size_t)76054528);   // 256 KB
  uint32_t* flags  = (uint32_t*)(ws + (size_t)76316672);   // 384 B

  init_kernel<<<3, 256, 0, stream>>>(vel_init, vd_w[0], vd_b[0], vd_w[1], vd_b[1],
                                     vd_w[2], vd_b[2], h0f, h0b, flags);

  ScanParams P;
  P.x = x;
  for (int l=0;l<3;++l){ P.wih[l]=w_ih[l]; P.whh[l]=w_hh[l]; P.bih[l]=b_ih[l]; P.bhh[l]=b_hh[l]; }
  P.h0f = h0f; P.h0b = h0b;
  P.ring0 = ring0; P.ring1 = ring1; P.out2 = out2; P.flags = flags;

  fused_scan<<<96, 128, 0, stream>>>(P);

  scores_kernel<<<(B_*T_)/4, 256, 0, stream>>>(out2, attn_w, attn_b, a1, scores);
  softmax_kernel<<<B_, 256, 0, stream>>>(scores, attnp);
  final_kernel<<<(B_*T_)/4, 256, 0, stream>>>(out2, x, attnp, dec_w, dec_b,
                                              vel_w, vel_b, std_w, std_b, a1, (float*)d_out);
}